// Round 5
// baseline (275.840 us; speedup 1.0000x reference)
//
#include <hip/hip_runtime.h>
#include <stdint.h>

typedef unsigned short u16;
typedef __bf16 bf16x8 __attribute__((ext_vector_type(8)));
typedef float f32x4 __attribute__((ext_vector_type(4)));

#define MM 2
#define NN 8
#define CC 1024
#define DD 256
#define BB 32
#define SS 512

__device__ __forceinline__ u16 f2bf(float f) {
  uint32_t u = __float_as_uint(f);
  u += 0x7FFFu + ((u >> 16) & 1u);   // round-to-nearest-even
  return (u16)(u >> 16);
}

__device__ __forceinline__ uint32_t pack2(float a, float b) {
  return (uint32_t)f2bf(a) | ((uint32_t)f2bf(b) << 16);
}

__device__ __forceinline__ void async16(const void* g, void* l) {
  __builtin_amdgcn_global_load_lds(
      (const __attribute__((address_space(1))) uint32_t*)g,
      (__attribute__((address_space(3))) uint32_t*)l, 16, 0, 0);
}

// ---------------- prep: weights transpose+cvt AND x fp32->bf16 ----------------
// blocks [0,2048): dw [16][1024][256] -> wdT bf16 [16][256][1024]
// blocks [2048,4096): uw [16][256][1024] -> wuT bf16 [16][1024][256]
// blocks [4096,6144): x fp32 [B,S,C] -> xb bf16 (same layout)
__global__ __launch_bounds__(256) void prep_w(
    const float* __restrict__ dw, u16* __restrict__ wdT,
    const float* __restrict__ uw, u16* __restrict__ wuT,
    const float* __restrict__ x, u16* __restrict__ xb) {
  int bid = blockIdx.x;
  if (bid >= 4096) {                 // ---- x conversion, fully coalesced ----
    const int t = bid - 4096;        // 2048 blocks x 2048 float4
    const float4* in4 = reinterpret_cast<const float4*>(x) + (size_t)t * 2048;
    uint2* out2 = reinterpret_cast<uint2*>(xb) + (size_t)t * 2048;
    const int tx = threadIdx.x;
#pragma unroll
    for (int k = 0; k < 8; ++k) {
      float4 v = in4[k * 256 + tx];
      out2[k * 256 + tx] = make_uint2(pack2(v.x, v.y), pack2(v.z, v.w));
    }
    return;
  }
  __shared__ float tile[64][33];
  const float* src; u16* dst; int K, N, tk, tn;
  if (bid < 2048) {
    K = CC; N = DD;
    const int slab = bid >> 7, t = bid & 127;   // 16 x 8 tiles per slab
    tk = t >> 3; tn = t & 7;
    src = dw + (size_t)slab * K * N;
    dst = wdT + (size_t)slab * K * N;
  } else {
    bid -= 2048;
    K = DD; N = CC;
    const int slab = bid >> 7, t = bid & 127;   // 4 x 32 tiles per slab
    tk = t >> 5; tn = t & 31;
    src = uw + (size_t)slab * K * N;
    dst = wuT + (size_t)slab * K * N;
  }
  const int k0 = tk * 64, n0 = tn * 32;
  const int tx = threadIdx.x & 31, ty = threadIdx.x >> 5;
#pragma unroll
  for (int i = 0; i < 64; i += 8)
    tile[ty + i][tx] = src[(size_t)(k0 + ty + i) * N + n0 + tx];
  __syncthreads();
  uint32_t* dst32 = reinterpret_cast<uint32_t*>(dst);
#pragma unroll
  for (int i = 0; i < 32; i += 8) {
    const int nr = ty + i;
    dst32[((size_t)(n0 + nr) * K + k0) / 2 + tx] =
        pack2(tile[2 * tx][nr], tile[2 * tx + 1][nr]);
  }
}

// ---------------- fused: u = silu(x@Wd + b) @ Wu, z kept in LDS -------------
// 128-row S-tiles, BK=64, 16+16 barrier-iterations. ALL staging (A and B) via
// global_load_lds: no in-loop pack VALU, no x-latency chain in the critical
// path. Flat 256-block grid with XCD-aware decode: XCD g owns b in
// [4g,4g+4) x both m x all 4 s-tiles (32 blocks = 32 CUs/XCD), so weights+x
// are XCD-L2-resident instead of 4x duplicated across XCDs.
// LDS = 160 KB: smA 2x16K, smB 2x32K, zl 64K. Tiles [row][64k] with 8-chunk
// XOR swizzle (chunk ^= row&7): DMA dest linear, global source pre-swizzled,
// frag reads apply the same involution.
__global__ __launch_bounds__(512, 2) void fused_adapter(
    const u16* __restrict__ xb, const u16* __restrict__ wdT,
    const u16* __restrict__ wuT, const float* __restrict__ db,
    const int* __restrict__ eidx, float* __restrict__ out) {
  __shared__ __align__(16) u16 smA[2][128 * 64];   // 2 x 16 KB: x staging (bf16)
  __shared__ __align__(16) u16 smB[2][256 * 64];   // 2 x 32 KB: weight staging
  __shared__ __align__(16) u16 zl[8 * 128 * 32];   // 64 KB: z (8 k-tiles)

  // XCD-aware decode of the flat 256-block grid
  const int id = blockIdx.x;
  const int xcd = id & 7;
  const int j5 = id >> 3;            // 0..31 within XCD
  const int stile = j5 >> 3;         // 0..3
  const int m = (j5 >> 2) & 1;
  const int b = xcd * 4 + (j5 & 3);
  const int pair = m * BB + b;
  const int e = eidx[pair];
  const int s0 = stile * 128;

  const int tid = threadIdx.x;
  const int lane = tid & 63;
  const int wave = tid >> 6;          // 0..7
  const int quad = lane >> 4;
  const int l16 = lane & 15;
  const int fx = (l16 >> 1) & 3;      // zl slot swizzle (16B slots in 32-k rows)
  const int fxr = l16 & 7;            // smA/smB chunk swizzle (8 chunks / 64-k row)

  const int wr = (wave >> 2) * 64;    // wave s-rows
  const int wc = (wave & 3) * 64;     // wave cols (d in ph1, c in ph2)

  const u16* Bd = wdT + (size_t)(m * NN + e) * DD * CC;   // [256 d x 1024 k]
  const u16* Bu = wuT + (size_t)(m * NN + e) * CC * DD;   // [1024 c x 256 k]

  const float* bias_p = db + (size_t)(m * NN + e) * DD;
  float biasr[4];
#pragma unroll
  for (int j = 0; j < 4; ++j) biasr[j] = bias_p[wc + j * 16 + l16];

  // DMA staging lane mapping: 8 lanes per row, source chunk pre-swizzled
  const int r_l = lane >> 3;          // 0..7: row within 8-row group
  const int sx = (lane & 7) ^ r_l;    // pre-swizzled source chunk

  // A: wave stages rows [wave*16, wave*16+16) of the 128-row x slab
  const u16* gA = xb + ((size_t)b * SS + s0 + wave * 16 + r_l) * CC + sx * 8;
  // B: wave stages rows [wave*32, wave*32+32)
  const u16* gBd = Bd + (size_t)(wave * 32 + r_l) * CC + sx * 8;
  const u16* gBu = Bu + (size_t)(wave * 32 + r_l) * DD + sx * 8;

  f32x4 acc[4][4];
#pragma unroll
  for (int i = 0; i < 4; ++i)
#pragma unroll
    for (int j = 0; j < 4; ++j) acc[i][j] = (f32x4){0.f, 0.f, 0.f, 0.f};

  // ---- prologue: stage A(0), B(0) ----
#pragma unroll
  for (int s = 0; s < 2; ++s)
    async16(gA + (size_t)(s * 8) * CC, &smA[0][(wave * 16 + s * 8) * 64]);
#pragma unroll
  for (int s = 0; s < 4; ++s)
    async16(gBd + (size_t)(s * 8) * CC, &smB[0][(wave * 32 + s * 8) * 64]);
  asm volatile("s_waitcnt vmcnt(0) lgkmcnt(0)" ::: "memory");
  __builtin_amdgcn_s_barrier();

  // ---- phase 1: K = 1024, 16 iters of BK=64 ----
  for (int kk = 0; kk < 16; ++kk) {
    const int cur = kk & 1, nxt = cur ^ 1;
    if (kk < 15) {                     // stage A(kk+1), B(kk+1)
      const int ko = (kk + 1) * 64;
#pragma unroll
      for (int s = 0; s < 2; ++s)
        async16(gA + (size_t)(s * 8) * CC + ko, &smA[nxt][(wave * 16 + s * 8) * 64]);
#pragma unroll
      for (int s = 0; s < 4; ++s)
        async16(gBd + (size_t)(s * 8) * CC + ko, &smB[nxt][(wave * 32 + s * 8) * 64]);
    } else {                           // stage phase-2 g=0 tile (ct=0, k=0..63)
#pragma unroll
      for (int s = 0; s < 4; ++s)
        async16(gBu + (size_t)(s * 8) * DD, &smB[nxt][(wave * 32 + s * 8) * 64]);
    }
#pragma unroll
    for (int h = 0; h < 2; ++h) {
      bf16x8 af[4], bfr[4];
#pragma unroll
      for (int i = 0; i < 4; ++i)
        af[i] = *reinterpret_cast<const bf16x8*>(
            &smA[cur][(wr + i * 16 + l16) * 64 + ((h * 4 + quad) ^ fxr) * 8]);
#pragma unroll
      for (int j = 0; j < 4; ++j)
        bfr[j] = *reinterpret_cast<const bf16x8*>(
            &smB[cur][(wc + j * 16 + l16) * 64 + ((h * 4 + quad) ^ fxr) * 8]);
      __builtin_amdgcn_s_setprio(1);
#pragma unroll
      for (int i = 0; i < 4; ++i)
#pragma unroll
        for (int j = 0; j < 4; ++j)
          acc[i][j] = __builtin_amdgcn_mfma_f32_16x16x32_bf16(af[i], bfr[j], acc[i][j], 0, 0, 0);
      __builtin_amdgcn_s_setprio(0);
    }
    asm volatile("s_waitcnt vmcnt(0) lgkmcnt(0)" ::: "memory");
    __builtin_amdgcn_s_barrier();
  }

  // ---- silu + bias, z -> LDS k-tile layout (swizzled) ----
#pragma unroll
  for (int j = 0; j < 4; ++j) {
    const int d = wc + j * 16 + l16;
    const int kt = d >> 5;
    const int kl = d & 31;
    const int slot0 = kl >> 3;
    const int kin = kl & 7;
#pragma unroll
    for (int i = 0; i < 4; ++i) {
      const int zr = wr + i * 16 + quad * 4;
#pragma unroll
      for (int r = 0; r < 4; ++r) {
        const int row = zr + r;
        float v = acc[i][j][r] + biasr[j];
        v = v / (1.f + __expf(-v));
        zl[kt * 4096 + row * 32 + ((slot0 ^ ((row >> 1) & 3)) * 8) + kin] = f2bf(v);
      }
    }
  }
  asm volatile("s_waitcnt lgkmcnt(0)" ::: "memory");
  __builtin_amdgcn_s_barrier();

  // ---- phase 2: 16 iters of BK=64 over (ct, it2) ----
  float* ob = out + ((size_t)pair * SS + s0) * CC;

  for (int g = 0; g < 16; ++g) {
    const int cur2 = g & 1, nxt2 = cur2 ^ 1;
    const int ct = g >> 2;
    const int it2 = g & 3;
    if (g < 15) {
      const int g2 = g + 1;
      const size_t ro = (size_t)(g2 >> 2) * 256 * DD + (g2 & 3) * 64;
#pragma unroll
      for (int s = 0; s < 4; ++s)
        async16(gBu + ro + (size_t)(s * 8) * DD, &smB[nxt2][(wave * 32 + s * 8) * 64]);
    }
    if (it2 == 0) {
#pragma unroll
      for (int i = 0; i < 4; ++i)
#pragma unroll
        for (int j = 0; j < 4; ++j) acc[i][j] = (f32x4){0.f, 0.f, 0.f, 0.f};
    }
#pragma unroll
    for (int h = 0; h < 2; ++h) {
      bf16x8 af[4], bfr[4];
#pragma unroll
      for (int i = 0; i < 4; ++i)
        af[i] = *reinterpret_cast<const bf16x8*>(
            &zl[(it2 * 2 + h) * 4096 + (wr + i * 16 + l16) * 32 + (quad ^ fx) * 8]);
#pragma unroll
      for (int j = 0; j < 4; ++j)
        bfr[j] = *reinterpret_cast<const bf16x8*>(
            &smB[cur2][(wc + j * 16 + l16) * 64 + ((h * 4 + quad) ^ fxr) * 8]);
      __builtin_amdgcn_s_setprio(1);
#pragma unroll
      for (int i = 0; i < 4; ++i)
#pragma unroll
        for (int j = 0; j < 4; ++j)
          acc[i][j] = __builtin_amdgcn_mfma_f32_16x16x32_bf16(af[i], bfr[j], acc[i][j], 0, 0, 0);
      __builtin_amdgcn_s_setprio(0);
    }
    if (it2 == 3) {
#pragma unroll
      for (int j = 0; j < 4; ++j) {
        const int c = ct * 256 + wc + j * 16 + l16;
#pragma unroll
        for (int i = 0; i < 4; ++i) {
          const int sr = wr + i * 16 + quad * 4;
#pragma unroll
          for (int r = 0; r < 4; ++r)
            ob[(size_t)(sr + r) * CC + c] = acc[i][j][r];
        }
      }
    }
    if (g < 15) {
      asm volatile("s_waitcnt vmcnt(0) lgkmcnt(0)" ::: "memory");
      __builtin_amdgcn_s_barrier();
    }
  }
}

extern "C" void kernel_launch(void* const* d_in, const int* in_sizes, int n_in,
                              void* d_out, int out_size, void* d_ws, size_t ws_size,
                              hipStream_t stream) {
  const float* x  = (const float*)d_in[0];  // [B,S,C]
  const int* eidx = (const int*)d_in[1];    // [M,B]
  const float* dw = (const float*)d_in[2];  // [M,N,C,D]
  const float* db = (const float*)d_in[3];  // [M,N,D]
  const float* uw = (const float*)d_in[4];  // [M,N,D,C]
  float* out = (float*)d_out;               // [M,B,S,C]

  char* ws = (char*)d_ws;
  u16* wdT = (u16*)(ws);                                   //  8 MB: [M,N,D,C] bf16
  u16* wuT = (u16*)(ws + (size_t)8 * 1024 * 1024);         //  8 MB: [M,N,C,D] bf16
  u16* xbf = (u16*)(ws + (size_t)16 * 1024 * 1024);        // 32 MB: [B,S,C] bf16

  prep_w<<<dim3(6144), dim3(256), 0, stream>>>(dw, wdT, uw, wuT, x, xbf);
  fused_adapter<<<dim3(256), dim3(512), 0, stream>>>(
      xbf, wdT, wuT, db, eidx, out);
}